// Round 5
// baseline (184.998 us; speedup 1.0000x reference)
//
#include <hip/hip_runtime.h>

// SelfAttention (SAGAN-style), MI355X — bf16 MFMA implementation, v5.
// Math: out[b,c,n] = gamma * sum_m [exp(S[m,n]) / Z[m]] * V[b,c,m] + x[b,c,n]
//   S[m,n] = sum_q Q[q,m] K[q,n],  Z[m] = sum_j exp(S[m,j]).
// exp2 trick: Q is pre-scaled by log2(e) at projection time, so
//   exp(S) = exp2(S'), and with L[m] = log2(1/Z[m]) folded into the MFMA
//   accumulator init, P[m,n] = exp2(S'[m,n] + L[m]) needs no extra VALU.
//
// MFMA shape: v_mfma_f32_16x16x32_bf16.
//   A-frag: A[i = lane&15][k = (lane>>4)*8 + j]
//   B-frag: B[k = (lane>>4)*8 + j][j = lane&15]
//   C/D:    col = lane&15, row = (lane>>4)*4 + reg

constexpr int Bn = 4, Cc = 64, Q8 = 8, Np = 4096;
constexpr int QK_STR = 32;  // padded q dim (shorts) per position
constexpr int PSTR = 40;    // attn Plds row stride in shorts (32 m + 8 pad)
constexpr int NSL = 4;      // zsum n-slices
constexpr int KSTR = 40;    // zsum Klds row stride in shorts (32 + 8 pad)

typedef float f32x4 __attribute__((ext_vector_type(4)));
typedef short short8 __attribute__((ext_vector_type(8)));

__device__ inline unsigned int f2bf(float x) {  // RNE f32->bf16 (as u16)
    unsigned int u = __float_as_uint(x);
    u += 0x7fff + ((u >> 16) & 1);
    return u >> 16;
}
__device__ inline float bf2f(unsigned int u) { return __uint_as_float(u << 16); }

__device__ inline unsigned cvt_pk_bf16(float a, float b) {  // lo=bf16(a), hi=bf16(b)
    unsigned r;
    asm("v_cvt_pk_bf16_f32 %0, %1, %2" : "=v"(r) : "v"(a), "v"(b));
    return r;
}
__device__ inline float exp2g(float x) {
#if __has_builtin(__builtin_amdgcn_exp2f)
    return __builtin_amdgcn_exp2f(x);
#else
    return exp2f(x);
#endif
}
__device__ inline float log2g(float x) {
#if __has_builtin(__builtin_amdgcn_logf)
    return __builtin_amdgcn_logf(x);
#else
    return log2f(x);
#endif
}

// ---------------- kernel 1: QKV projections, lane-per-position ----------------
// Q is scaled by log2(e) so downstream exponentials are pure exp2.
__global__ __launch_bounds__(64) void qkv_v2(
    const float* __restrict__ x,
    const float* __restrict__ Wq, const float* __restrict__ bq,
    const float* __restrict__ Wk, const float* __restrict__ bk,
    const float* __restrict__ Wv, const float* __restrict__ bv,
    unsigned short* __restrict__ Qp, unsigned short* __restrict__ Kp,
    unsigned short* __restrict__ Vb)
{
    const int lane = threadIdx.x;
    const int gpos = blockIdx.x * 64;        // over Bn*Np
    const int os = blockIdx.y;               // uniform -> scalar W loads
    const int b = gpos >> 12, n = (gpos & (Np - 1)) + lane;
    const float LOG2E = 1.4426950408889634f;

    float xv[Cc];
    const float* xp = x + (size_t)(b * Cc) * Np + n;
    #pragma unroll
    for (int c = 0; c < Cc; c++) xv[c] = xp[(size_t)c * Np];

    if (os == 0) {
        unsigned pk[4];
        float a0, a1;
        #pragma unroll
        for (int p = 0; p < 4; p++) {
            a0 = bq[2 * p]; a1 = bq[2 * p + 1];
            #pragma unroll
            for (int c = 0; c < Cc; c++) {
                a0 += Wq[(2 * p) * Cc + c] * xv[c];
                a1 += Wq[(2 * p + 1) * Cc + c] * xv[c];
            }
            pk[p] = f2bf(a0 * LOG2E) | (f2bf(a1 * LOG2E) << 16);
        }
        unsigned short* qrow = Qp + (size_t)(b * Np + n) * QK_STR;
        *(uint4*)qrow = make_uint4(pk[0], pk[1], pk[2], pk[3]);
        *(uint4*)(qrow + 8)  = make_uint4(0, 0, 0, 0);
        *(uint4*)(qrow + 16) = make_uint4(0, 0, 0, 0);
        *(uint4*)(qrow + 24) = make_uint4(0, 0, 0, 0);
        #pragma unroll
        for (int p = 0; p < 4; p++) {
            a0 = bk[2 * p]; a1 = bk[2 * p + 1];
            #pragma unroll
            for (int c = 0; c < Cc; c++) {
                a0 += Wk[(2 * p) * Cc + c] * xv[c];
                a1 += Wk[(2 * p + 1) * Cc + c] * xv[c];
            }
            pk[p] = f2bf(a0) | (f2bf(a1) << 16);
        }
        unsigned short* krow = Kp + (size_t)(b * Np + n) * QK_STR;
        *(uint4*)krow = make_uint4(pk[0], pk[1], pk[2], pk[3]);
        *(uint4*)(krow + 8)  = make_uint4(0, 0, 0, 0);
        *(uint4*)(krow + 16) = make_uint4(0, 0, 0, 0);
        *(uint4*)(krow + 24) = make_uint4(0, 0, 0, 0);
        #pragma unroll
        for (int o = 0; o < 4; o++) {
            float a = bv[o];
            #pragma unroll
            for (int c = 0; c < Cc; c++) a += Wv[o * Cc + c] * xv[c];
            Vb[(size_t)(b * Cc + o) * Np + n] = (unsigned short)f2bf(a);
        }
    } else {
        const int vbase = os * 20 - 16;      // 4, 24, 44
        #pragma unroll 4
        for (int o = 0; o < 20; o++) {
            const int vr = vbase + o;
            float a = bv[vr];
            #pragma unroll
            for (int c = 0; c < Cc; c++) a += Wv[vr * Cc + c] * xv[c];
            Vb[(size_t)(b * Cc + vr) * Np + n] = (unsigned short)f2bf(a);
        }
    }
}

// ---------------- kernel 2: Z partials via MFMA + shared LDS K stream ----------------
__global__ __launch_bounds__(256) void zsum_v2(
    const unsigned short* __restrict__ Qp, const unsigned short* __restrict__ Kp,
    float* __restrict__ ZP)
{
    __shared__ unsigned short Klds[64 * KSTR];
    const int tid = threadIdx.x, w = tid >> 6, lane = tid & 63;
    const int quad = lane >> 4, l15 = lane & 15;
    const int bz = blockIdx.z, ns = blockIdx.y;
    const int m0 = blockIdx.x * 64 + w * 16;

    short8 qa = *(const short8*)&Qp[((size_t)(bz * Np + m0 + l15)) * QK_STR + quad * 8];

    const int rt = tid >> 2, ct = tid & 3;   // staging: row rt, 8-short chunk ct
    const int nbase = ns * (Np / NSL);
    const unsigned short* kbase = Kp + (size_t)bz * Np * QK_STR;

    uint4 pf = *(const uint4*)&kbase[(size_t)(nbase + rt) * QK_STR + ct * 8];
    float z0 = 0.f, z1 = 0.f, z2 = 0.f, z3 = 0.f;
    for (int nt = 0; nt < Np / NSL; nt += 64) {
        *(uint4*)&Klds[rt * KSTR + ct * 8] = pf;
        __syncthreads();
        if (nt + 64 < Np / NSL)
            pf = *(const uint4*)&kbase[(size_t)(nbase + nt + 64 + rt) * QK_STR + ct * 8];
        #pragma unroll
        for (int t16 = 0; t16 < 4; t16++) {
            short8 kb = *(const short8*)&Klds[(t16 * 16 + l15) * KSTR + quad * 8];
            f32x4 s = __builtin_amdgcn_mfma_f32_16x16x32_bf16(
                qa, kb, f32x4{0.f, 0.f, 0.f, 0.f}, 0, 0, 0);
            z0 += exp2g(s[0]); z1 += exp2g(s[1]);
            z2 += exp2g(s[2]); z3 += exp2g(s[3]);
        }
        __syncthreads();
    }
    #pragma unroll
    for (int mask = 1; mask < 16; mask <<= 1) {
        z0 += __shfl_xor(z0, mask); z1 += __shfl_xor(z1, mask);
        z2 += __shfl_xor(z2, mask); z3 += __shfl_xor(z3, mask);
    }
    if (l15 == 0) {
        float4 v = make_float4(z0, z1, z2, z3);
        *(float4*)&ZP[((size_t)(bz * NSL + ns)) * Np + m0 + quad * 4] = v;
    }
}

// ---------------- kernel 3: L[m] = log2(1/Z[m]) ----------------
__global__ __launch_bounds__(256) void zred(
    const float* __restrict__ ZP, float* __restrict__ Lg)
{
    int i = blockIdx.x * 256 + threadIdx.x;  // over Bn*Np
    int b = i >> 12, m = i & (Np - 1);
    float z = 0.f;
    #pragma unroll
    for (int s = 0; s < NSL; s++) z += ZP[((size_t)(b * NSL + s)) * Np + m];
    Lg[(size_t)b * Np + m] = -log2g(z);
}

// ---------------- kernel 4: out partials via MFMA, barrier-free ----------------
// grid (Np/64, SL, Bn), block 256 (4 waves). Wave w owns 16 n (rows w*16.. of Plds).
__global__ __launch_bounds__(256) void attn_v2(
    const unsigned short* __restrict__ Qp, const unsigned short* __restrict__ Kp,
    const unsigned short* __restrict__ Vb, const float* __restrict__ Lg,
    unsigned short* __restrict__ PO, int Ms, int SL)
{
    __shared__ unsigned short Plds[64 * PSTR];  // [n_local][m_local], wave-private rows
    const int tid = threadIdx.x, w = tid >> 6, lane = tid & 63;
    const int quad = lane >> 4, l15 = lane & 15;
    const int bz = blockIdx.z, by = blockIdx.y, nb = blockIdx.x * 64;
    const int nl = w * 16 + l15;                // local n row

    // loop-invariant K B-frag for this wave's 16-n subtile
    short8 kf = *(const short8*)&Kp[((size_t)(bz * Np + nb + nl)) * QK_STR + quad * 8];

    f32x4 acc[4];
    #pragma unroll
    for (int ct = 0; ct < 4; ct++) acc[ct] = f32x4{0.f, 0.f, 0.f, 0.f};

    const int m_base = by * Ms;
    for (int mi = 0; mi < Ms; mi += 32) {
        const int m0 = m_base + mi;
        // phase 1: P[m0..m0+31][wave's 16 n] = exp2(S' + L[m]), bf16, into LDS
        #pragma unroll
        for (int mt = 0; mt < 2; mt++) {
            short8 qa = *(const short8*)
                &Qp[((size_t)(bz * Np + m0 + mt * 16 + l15)) * QK_STR + quad * 8];
            f32x4 Lc = *(const f32x4*)
                &Lg[(size_t)bz * Np + m0 + mt * 16 + quad * 4];
            f32x4 s = __builtin_amdgcn_mfma_f32_16x16x32_bf16(qa, kf, Lc, 0, 0, 0);
            unsigned p01 = cvt_pk_bf16(exp2g(s[0]), exp2g(s[1]));
            unsigned p23 = cvt_pk_bf16(exp2g(s[2]), exp2g(s[3]));
            *(uint2*)&Plds[nl * PSTR + mt * 16 + quad * 4] = make_uint2(p01, p23);
        }
        // phase 2: acc[c, n] += V[c, m0..31] * P[m0..31, n]  (wave-private rows)
        short8 pb = *(const short8*)&Plds[nl * PSTR + quad * 8];
        #pragma unroll
        for (int ct = 0; ct < 4; ct++) {
            short8 ua = *(const short8*)
                &Vb[((size_t)(bz * Cc + ct * 16 + l15)) * Np + m0 + quad * 8];
            acc[ct] = __builtin_amdgcn_mfma_f32_16x16x32_bf16(ua, pb, acc[ct], 0, 0, 0);
        }
    }
    unsigned short* po = PO + ((size_t)((bz * SL + by) * Cc)) * Np + nb;
    #pragma unroll
    for (int ct = 0; ct < 4; ct++) {
        int c = ct * 16 + quad * 4;
        #pragma unroll
        for (int r = 0; r < 4; r++)
            po[(size_t)(c + r) * Np + nl] = (unsigned short)f2bf(acc[ct][r]);
    }
}

// ---------------- kernel 5: combine slices + gamma*out + x (8-wide) ----------------
__global__ __launch_bounds__(256) void combine_kernel(
    const unsigned short* __restrict__ PO, const float* __restrict__ x,
    const float* __restrict__ gamma, float* __restrict__ out, int sl2)
{
    int idx8 = (blockIdx.x * 256 + threadIdx.x) * 8;  // over Bn*Cc*Np
    int b = idx8 >> 18;
    int c = (idx8 >> 12) & 63;
    int n = idx8 & (Np - 1);
    float o[8];
    #pragma unroll
    for (int i = 0; i < 8; i++) o[i] = 0.f;
    for (int sl = 0; sl < sl2; ++sl) {
        uint4 u = *(const uint4*)&PO[(size_t)((b * sl2 + sl) * Cc + c) * Np + n];
        o[0] += bf2f(u.x & 0xffff); o[1] += bf2f(u.x >> 16);
        o[2] += bf2f(u.y & 0xffff); o[3] += bf2f(u.y >> 16);
        o[4] += bf2f(u.z & 0xffff); o[5] += bf2f(u.z >> 16);
        o[6] += bf2f(u.w & 0xffff); o[7] += bf2f(u.w >> 16);
    }
    float g = gamma[0];
    float4 x0 = *(const float4*)&x[idx8];
    float4 x1 = *(const float4*)&x[idx8 + 4];
    float4 r0 = make_float4(g * o[0] + x0.x, g * o[1] + x0.y,
                            g * o[2] + x0.z, g * o[3] + x0.w);
    float4 r1 = make_float4(g * o[4] + x1.x, g * o[5] + x1.y,
                            g * o[6] + x1.z, g * o[7] + x1.w);
    *(float4*)&out[idx8] = r0;
    *(float4*)&out[idx8 + 4] = r1;
}

extern "C" void kernel_launch(void* const* d_in, const int* in_sizes, int n_in,
                              void* d_out, int out_size, void* d_ws, size_t ws_size,
                              hipStream_t stream)
{
    const float* x     = (const float*)d_in[0];
    const float* Wq    = (const float*)d_in[1];
    const float* bq    = (const float*)d_in[2];
    const float* Wk    = (const float*)d_in[3];
    const float* bk    = (const float*)d_in[4];
    const float* Wv    = (const float*)d_in[5];
    const float* bv    = (const float*)d_in[6];
    const float* gamma = (const float*)d_in[7];
    float* out = (float*)d_out;

    unsigned short* Qp = (unsigned short*)d_ws;               // 1 MB
    unsigned short* Kp = Qp + (size_t)Bn * Np * QK_STR;       // 1 MB
    unsigned short* Vb = Kp + (size_t)Bn * Np * QK_STR;       // 2 MB (bf16 V, unnormalized)
    float* Lg   = (float*)(Vb + (size_t)Bn * Cc * Np);        // 64 KB: log2(1/Z)
    float* ZP   = Lg + (size_t)Bn * Np;                       // NSL partials, 256 KB
    unsigned short* PO = (unsigned short*)(ZP + (size_t)Bn * NSL * Np);  // SL * 2 MB

    size_t baseB = (size_t)Bn * Np * QK_STR * 2 * 2 + (size_t)Bn * Cc * Np * 2
                 + (size_t)Bn * Np * 4 + (size_t)Bn * NSL * Np * 4;
    int SL = 4;  // m-slices for attn partials
    while (SL > 1 && baseB + (size_t)Bn * SL * Cc * Np * 2 > ws_size) SL >>= 1;

    qkv_v2<<<dim3(Bn * Np / 64, 4), 64, 0, stream>>>(x, Wq, bq, Wk, bk, Wv, bv,
                                                     Qp, Kp, Vb);
    zsum_v2<<<dim3(Np / 64, NSL, Bn), 256, 0, stream>>>(Qp, Kp, ZP);
    zred<<<Bn * Np / 256, 256, 0, stream>>>(ZP, Lg);
    attn_v2<<<dim3(Np / 64, SL, Bn), 256, 0, stream>>>(Qp, Kp, Vb, Lg,
                                                       PO, Np / SL, SL);
    combine_kernel<<<Bn * Cc * Np / (256 * 8), 256, 0, stream>>>(PO, x, gamma, out, SL);
}

// Round 8
// 146.818 us; speedup vs baseline: 1.2600x; 1.2600x over previous
//
#include <hip/hip_runtime.h>

// SelfAttention (SAGAN-style), MI355X — bf16 MFMA implementation, v8.
// Math: out[b,c,n] = gamma * sum_m [exp(S[m,n]) / Z[m]] * V[b,c,m] + x[b,c,n]
//   S[m,n] = sum_q Q[q,m] K[q,n],  Z[m] = sum_j exp(S[m,j]).
// exp2 trick: Q pre-scaled by log2(e); L[m] = -log2(Z[m]) folded into the
// S-MFMA accumulator init => P = exp2(S' + L) with zero extra VALU.
//
// v8 notes: v6/v7 (512-thread 8-wave attn, SL=8) failed correctness for
// reasons not identified by inspection; both the R3 geometry (4 waves,
// 128 n/block, 32 n/wave, SL=4) and the v5 epilogue (Lc-in-accumulator,
// exp2, v_cvt_pk_bf16_f32, bf16 PO) passed independently — v8 is exactly
// their composition. Do not re-introduce 512-thread attn blocks without a
// standalone correctness probe.

constexpr int Bn = 4, Cc = 64, Q8 = 8, Np = 4096;
constexpr int QK_STR = 32;  // padded q dim (shorts) per position
constexpr int PSTR = 40;    // attn Plds row stride in shorts (80B, 16B-aligned)
constexpr int NSL = 4;      // zsum n-slices
constexpr int KSTR = 40;    // zsum Klds row stride in shorts

typedef float f32x4 __attribute__((ext_vector_type(4)));
typedef short short8 __attribute__((ext_vector_type(8)));

__device__ inline unsigned int f2bf(float x) {  // RNE f32->bf16 (as u16)
    unsigned int u = __float_as_uint(x);
    u += 0x7fff + ((u >> 16) & 1);
    return u >> 16;
}
__device__ inline float bf2f(unsigned int u) { return __uint_as_float(u << 16); }

__device__ inline unsigned cvt_pk_bf16(float a, float b) {  // lo=bf16(a), hi=bf16(b)
    unsigned r;
    asm("v_cvt_pk_bf16_f32 %0, %1, %2" : "=v"(r) : "v"(a), "v"(b));
    return r;
}
__device__ inline float exp2g(float x) {
#if __has_builtin(__builtin_amdgcn_exp2f)
    return __builtin_amdgcn_exp2f(x);
#else
    return exp2f(x);
#endif
}
__device__ inline float log2g(float x) {
#if __has_builtin(__builtin_amdgcn_logf)
    return __builtin_amdgcn_logf(x);
#else
    return log2f(x);
#endif
}

// ---------------- kernel 1: QKV projections, lane-per-position ----------------
__global__ __launch_bounds__(64) void qkv_v2(
    const float* __restrict__ x,
    const float* __restrict__ Wq, const float* __restrict__ bq,
    const float* __restrict__ Wk, const float* __restrict__ bk,
    const float* __restrict__ Wv, const float* __restrict__ bv,
    unsigned short* __restrict__ Qp, unsigned short* __restrict__ Kp,
    unsigned short* __restrict__ Vb)
{
    const int lane = threadIdx.x;
    const int gpos = blockIdx.x * 64;        // over Bn*Np
    const int os = blockIdx.y;               // uniform -> scalar W loads
    const int b = gpos >> 12, n = (gpos & (Np - 1)) + lane;
    const float LOG2E = 1.4426950408889634f;

    float xv[Cc];
    const float* xp = x + (size_t)(b * Cc) * Np + n;
    #pragma unroll
    for (int c = 0; c < Cc; c++) xv[c] = xp[(size_t)c * Np];

    if (os == 0) {
        unsigned pk[4];
        float a0, a1;
        #pragma unroll
        for (int p = 0; p < 4; p++) {
            a0 = bq[2 * p]; a1 = bq[2 * p + 1];
            #pragma unroll
            for (int c = 0; c < Cc; c++) {
                a0 += Wq[(2 * p) * Cc + c] * xv[c];
                a1 += Wq[(2 * p + 1) * Cc + c] * xv[c];
            }
            pk[p] = f2bf(a0 * LOG2E) | (f2bf(a1 * LOG2E) << 16);
        }
        unsigned short* qrow = Qp + (size_t)(b * Np + n) * QK_STR;
        *(uint4*)qrow = make_uint4(pk[0], pk[1], pk[2], pk[3]);
        *(uint4*)(qrow + 8)  = make_uint4(0, 0, 0, 0);
        *(uint4*)(qrow + 16) = make_uint4(0, 0, 0, 0);
        *(uint4*)(qrow + 24) = make_uint4(0, 0, 0, 0);
        #pragma unroll
        for (int p = 0; p < 4; p++) {
            a0 = bk[2 * p]; a1 = bk[2 * p + 1];
            #pragma unroll
            for (int c = 0; c < Cc; c++) {
                a0 += Wk[(2 * p) * Cc + c] * xv[c];
                a1 += Wk[(2 * p + 1) * Cc + c] * xv[c];
            }
            pk[p] = f2bf(a0) | (f2bf(a1) << 16);
        }
        unsigned short* krow = Kp + (size_t)(b * Np + n) * QK_STR;
        *(uint4*)krow = make_uint4(pk[0], pk[1], pk[2], pk[3]);
        *(uint4*)(krow + 8)  = make_uint4(0, 0, 0, 0);
        *(uint4*)(krow + 16) = make_uint4(0, 0, 0, 0);
        *(uint4*)(krow + 24) = make_uint4(0, 0, 0, 0);
        #pragma unroll
        for (int o = 0; o < 4; o++) {
            float a = bv[o];
            #pragma unroll
            for (int c = 0; c < Cc; c++) a += Wv[o * Cc + c] * xv[c];
            Vb[(size_t)(b * Cc + o) * Np + n] = (unsigned short)f2bf(a);
        }
    } else {
        const int vbase = os * 20 - 16;      // 4, 24, 44
        #pragma unroll 4
        for (int o = 0; o < 20; o++) {
            const int vr = vbase + o;
            float a = bv[vr];
            #pragma unroll
            for (int c = 0; c < Cc; c++) a += Wv[vr * Cc + c] * xv[c];
            Vb[(size_t)(b * Cc + vr) * Np + n] = (unsigned short)f2bf(a);
        }
    }
}

// ---------------- kernel 2: Z partials via MFMA + shared LDS K stream ----------------
__global__ __launch_bounds__(256) void zsum_v2(
    const unsigned short* __restrict__ Qp, const unsigned short* __restrict__ Kp,
    float* __restrict__ ZP)
{
    __shared__ unsigned short Klds[64 * KSTR];
    const int tid = threadIdx.x, w = tid >> 6, lane = tid & 63;
    const int quad = lane >> 4, l15 = lane & 15;
    const int bz = blockIdx.z, ns = blockIdx.y;
    const int m0 = blockIdx.x * 64 + w * 16;

    short8 qa = *(const short8*)&Qp[((size_t)(bz * Np + m0 + l15)) * QK_STR + quad * 8];

    const int rt = tid >> 2, ct = tid & 3;   // staging: row rt, 8-short chunk ct
    const int nbase = ns * (Np / NSL);
    const unsigned short* kbase = Kp + (size_t)bz * Np * QK_STR;

    uint4 pf = *(const uint4*)&kbase[(size_t)(nbase + rt) * QK_STR + ct * 8];
    float z0 = 0.f, z1 = 0.f, z2 = 0.f, z3 = 0.f;
    for (int nt = 0; nt < Np / NSL; nt += 64) {
        *(uint4*)&Klds[rt * KSTR + ct * 8] = pf;
        __syncthreads();
        if (nt + 64 < Np / NSL)
            pf = *(const uint4*)&kbase[(size_t)(nbase + nt + 64 + rt) * QK_STR + ct * 8];
        #pragma unroll
        for (int t16 = 0; t16 < 4; t16++) {
            short8 kb = *(const short8*)&Klds[(t16 * 16 + l15) * KSTR + quad * 8];
            f32x4 s = __builtin_amdgcn_mfma_f32_16x16x32_bf16(
                qa, kb, f32x4{0.f, 0.f, 0.f, 0.f}, 0, 0, 0);
            z0 += exp2g(s[0]); z1 += exp2g(s[1]);
            z2 += exp2g(s[2]); z3 += exp2g(s[3]);
        }
        __syncthreads();
    }
    #pragma unroll
    for (int mask = 1; mask < 16; mask <<= 1) {
        z0 += __shfl_xor(z0, mask); z1 += __shfl_xor(z1, mask);
        z2 += __shfl_xor(z2, mask); z3 += __shfl_xor(z3, mask);
    }
    if (l15 == 0) {
        float4 v = make_float4(z0, z1, z2, z3);
        *(float4*)&ZP[((size_t)(bz * NSL + ns)) * Np + m0 + quad * 4] = v;
    }
}

// ---------------- kernel 3: L[m] = -log2(Z[m]) ----------------
__global__ __launch_bounds__(256) void zred(
    const float* __restrict__ ZP, float* __restrict__ Lg)
{
    int i = blockIdx.x * 256 + threadIdx.x;  // over Bn*Np
    int b = i >> 12, m = i & (Np - 1);
    float z = 0.f;
    #pragma unroll
    for (int s = 0; s < NSL; s++) z += ZP[((size_t)(b * NSL + s)) * Np + m];
    Lg[(size_t)b * Np + m] = -log2g(z);
}

// ---------------- kernel 4: out partials via MFMA, barrier-free ----------------
// R3-proven geometry: grid (Np/128, SL, Bn), block 256 (4 waves),
// wave w owns 32 n (two 16-n subtiles); Plds rows wave-private.
__global__ __launch_bounds__(256) void attn_v4(
    const unsigned short* __restrict__ Qp, const unsigned short* __restrict__ Kp,
    const unsigned short* __restrict__ Vb, const float* __restrict__ Lg,
    unsigned short* __restrict__ PO, int Ms, int SL)
{
    __shared__ unsigned short Plds[128 * PSTR];  // [n_local][m_local]
    const int tid = threadIdx.x, w = tid >> 6, lane = tid & 63;
    const int quad = lane >> 4, l15 = lane & 15;
    const int bz = blockIdx.z, by = blockIdx.y, nb = blockIdx.x * 128;

    // loop-invariant K B-frags for this wave's two 16-n subtiles
    short8 kf[2];
    #pragma unroll
    for (int t = 0; t < 2; t++) {
        int n = nb + (2 * w + t) * 16 + l15;
        kf[t] = *(const short8*)&Kp[((size_t)(bz * Np + n)) * QK_STR + quad * 8];
    }
    f32x4 acc[4][2];
    #pragma unroll
    for (int ct = 0; ct < 4; ct++)
        #pragma unroll
        for (int t = 0; t < 2; t++) acc[ct][t] = f32x4{0.f, 0.f, 0.f, 0.f};

    const int m_base = by * Ms;
    for (int mi = 0; mi < Ms; mi += 32) {
        const int m0 = m_base + mi;
        // phase 1: P[m0..m0+31][wave's 32 n] = exp2(S' + L[m]), bf16, into LDS
        #pragma unroll
        for (int mt = 0; mt < 2; mt++) {
            short8 qa = *(const short8*)
                &Qp[((size_t)(bz * Np + m0 + mt * 16 + l15)) * QK_STR + quad * 8];
            f32x4 Lc = *(const f32x4*)
                &Lg[(size_t)bz * Np + m0 + mt * 16 + quad * 4];
            #pragma unroll
            for (int t = 0; t < 2; t++) {
                f32x4 s = __builtin_amdgcn_mfma_f32_16x16x32_bf16(qa, kf[t], Lc, 0, 0, 0);
                unsigned p01 = cvt_pk_bf16(exp2g(s[0]), exp2g(s[1]));
                unsigned p23 = cvt_pk_bf16(exp2g(s[2]), exp2g(s[3]));
                int nl = (2 * w + t) * 16 + l15;
                *(uint2*)&Plds[nl * PSTR + mt * 16 + quad * 4] = make_uint2(p01, p23);
            }
        }
        // phase 2: acc[c, n] += V[c, m0..31] * P[m0..31, n]  (wave-private rows)
        short8 pb[2];
        #pragma unroll
        for (int t = 0; t < 2; t++)
            pb[t] = *(const short8*)&Plds[(w * 32 + t * 16 + l15) * PSTR + quad * 8];
        #pragma unroll
        for (int ct = 0; ct < 4; ct++) {
            short8 ua = *(const short8*)
                &Vb[((size_t)(bz * Cc + ct * 16 + l15)) * Np + m0 + quad * 8];
            #pragma unroll
            for (int t = 0; t < 2; t++)
                acc[ct][t] = __builtin_amdgcn_mfma_f32_16x16x32_bf16(
                    ua, pb[t], acc[ct][t], 0, 0, 0);
        }
    }
    unsigned short* po = PO + ((size_t)((bz * SL + by) * Cc)) * Np + nb;
    #pragma unroll
    for (int ct = 0; ct < 4; ct++)
        #pragma unroll
        for (int t = 0; t < 2; t++) {
            int c = ct * 16 + quad * 4, n = w * 32 + t * 16 + l15;
            #pragma unroll
            for (int r = 0; r < 4; r++)
                po[(size_t)(c + r) * Np + n] = (unsigned short)f2bf(acc[ct][t][r]);
        }
}

// ---------------- kernel 5: combine slices + gamma*out + x (8-wide) ----------------
__global__ __launch_bounds__(256) void combine_kernel(
    const unsigned short* __restrict__ PO, const float* __restrict__ x,
    const float* __restrict__ gamma, float* __restrict__ out, int sl2)
{
    int idx8 = (blockIdx.x * 256 + threadIdx.x) * 8;  // over Bn*Cc*Np
    int b = idx8 >> 18;
    int c = (idx8 >> 12) & 63;
    int n = idx8 & (Np - 1);
    float o[8];
    #pragma unroll
    for (int i = 0; i < 8; i++) o[i] = 0.f;
    for (int sl = 0; sl < sl2; ++sl) {
        uint4 u = *(const uint4*)&PO[(size_t)((b * sl2 + sl) * Cc + c) * Np + n];
        o[0] += bf2f(u.x & 0xffff); o[1] += bf2f(u.x >> 16);
        o[2] += bf2f(u.y & 0xffff); o[3] += bf2f(u.y >> 16);
        o[4] += bf2f(u.z & 0xffff); o[5] += bf2f(u.z >> 16);
        o[6] += bf2f(u.w & 0xffff); o[7] += bf2f(u.w >> 16);
    }
    float g = gamma[0];
    float4 x0 = *(const float4*)&x[idx8];
    float4 x1 = *(const float4*)&x[idx8 + 4];
    float4 r0 = make_float4(g * o[0] + x0.x, g * o[1] + x0.y,
                            g * o[2] + x0.z, g * o[3] + x0.w);
    float4 r1 = make_float4(g * o[4] + x1.x, g * o[5] + x1.y,
                            g * o[6] + x1.z, g * o[7] + x1.w);
    *(float4*)&out[idx8] = r0;
    *(float4*)&out[idx8 + 4] = r1;
}

extern "C" void kernel_launch(void* const* d_in, const int* in_sizes, int n_in,
                              void* d_out, int out_size, void* d_ws, size_t ws_size,
                              hipStream_t stream)
{
    const float* x     = (const float*)d_in[0];
    const float* Wq    = (const float*)d_in[1];
    const float* bq    = (const float*)d_in[2];
    const float* Wk    = (const float*)d_in[3];
    const float* bk    = (const float*)d_in[4];
    const float* Wv    = (const float*)d_in[5];
    const float* bv    = (const float*)d_in[6];
    const float* gamma = (const float*)d_in[7];
    float* out = (float*)d_out;

    unsigned short* Qp = (unsigned short*)d_ws;               // 1 MB
    unsigned short* Kp = Qp + (size_t)Bn * Np * QK_STR;       // 1 MB
    unsigned short* Vb = Kp + (size_t)Bn * Np * QK_STR;       // 2 MB (bf16 V, unnormalized)
    float* Lg   = (float*)(Vb + (size_t)Bn * Cc * Np);        // 64 KB: -log2(Z)
    float* ZP   = Lg + (size_t)Bn * Np;                       // NSL partials, 256 KB
    unsigned short* PO = (unsigned short*)(ZP + (size_t)Bn * NSL * Np);  // SL * 2 MB

    size_t baseB = (size_t)Bn * Np * QK_STR * 2 * 2 + (size_t)Bn * Cc * Np * 2
                 + (size_t)Bn * Np * 4 + (size_t)Bn * NSL * Np * 4;
    int SL = 4;  // m-slices for attn partials (R3-proven)
    while (SL > 1 && baseB + (size_t)Bn * SL * Cc * Np * 2 > ws_size) SL >>= 1;

    qkv_v2<<<dim3(Bn * Np / 64, 4), 64, 0, stream>>>(x, Wq, bq, Wk, bk, Wv, bv,
                                                     Qp, Kp, Vb);
    zsum_v2<<<dim3(Np / 64, NSL, Bn), 256, 0, stream>>>(Qp, Kp, ZP);
    zred<<<Bn * Np / 256, 256, 0, stream>>>(ZP, Lg);
    attn_v4<<<dim3(Np / 128, SL, Bn), 256, 0, stream>>>(Qp, Kp, Vb, Lg,
                                                        PO, Np / SL, SL);
    combine_kernel<<<Bn * Cc * Np / (256 * 8), 256, 0, stream>>>(PO, x, gamma, out, SL);
}